// Round 16
// baseline (109.591 us; speedup 1.0000x reference)
//
#include <hip/hip_runtime.h>
#include <math.h>

// QuanvolutionHybrid: conv2x2/s2 -> reshape(196,4) -> L2 norm ->
// all-pairs cos^2 >= 0.8 -> degree -> concat(784+196) -> linear(10) -> log_softmax
// R16: R14 (proven MFMA pair phase, 52us) + ONLY the pinned zero C-operand.
//      R15 stacked two changes and broke: count asm reading MFMA dest regs
//      crosses the MFMA->VALU hazard without compiler-inserted waits
//      (R12's identical asm read VALU-produced values -> correct). Counting
//      stays plain C (compiler owns the hazard); zero-init tax removed via
//      persistent zacc (no 16x v_mov re-zero per MFMA).

#define NP 196
#define FEAT 980
#define COS_TH 0.894427190999915878f   // sqrt(0.8)

typedef short v4s  __attribute__((ext_vector_type(4)));
typedef short v8s  __attribute__((ext_vector_type(8)));
typedef float v16f __attribute__((ext_vector_type(16)));

__global__ __launch_bounds__(256, 6) void quanv_kernel(
    const float* __restrict__ x,        // (8192, 784)
    const float* __restrict__ conv_w,   // (4,1,2,2) = 16
    const float* __restrict__ conv_b,   // (4,)
    const float* __restrict__ lin_w,    // (10, 980)
    const float* __restrict__ lin_b,    // (10,)
    float* __restrict__ out)            // (8192, 10)
{
    // s_x[img] dead after phase 2 -> late-phase overlays live on it.
    __shared__ __align__(16) float s_x[2][784];
    __shared__ __align__(16) short s_P[2][224][8];  // bf16 row: h0..h3, l0..l3
    __shared__ __align__(16) float s_feats[2][FEAT];

    const int b = blockIdx.x;            // 4096 blocks, 2 images each
    const int t = threadIdx.x;
    const int w = t >> 6, l = t & 63;

    // ---- Phase 1: stage both images ----
    if (t < NP) {
        ((float4*)s_x[0])[t] = ((const float4*)(x + (size_t)(2 * b)     * 784))[t];
        ((float4*)s_x[1])[t] = ((const float4*)(x + (size_t)(2 * b + 1) * 784))[t];
    }
    __syncthreads();

    // ---- Phase 2: conv both -> s_feats[img][0..784) channel-major ----
    if (t < NP) {
        int h = t / 14, ww = t - 14 * (t / 14);
        #pragma unroll
        for (int img = 0; img < 2; ++img) {
            const float* r0 = s_x[img] + (2 * h) * 28 + 2 * ww;
            float x00 = r0[0], x01 = r0[1], x10 = r0[28], x11 = r0[29];
            #pragma unroll
            for (int c = 0; c < 4; ++c) {
                float f = conv_b[c]
                        + conv_w[c * 4 + 0] * x00 + conv_w[c * 4 + 1] * x01
                        + conv_w[c * 4 + 2] * x10 + conv_w[c * 4 + 3] * x11;
                s_feats[img][c * NP + t] = f;
            }
        }
    }
    __syncthreads();   // s_x dead; overlays usable after this barrier

    // ---- Phase 3: normalize + exact bf16 hi/lo split -> s_P (rows 196..223 = 0) ----
    if (t < 224) {
        #pragma unroll
        for (int img = 0; img < 2; ++img) {
            v8s pk = {0, 0, 0, 0, 0, 0, 0, 0};
            if (t < NP) {
                float4 v = ((const float4*)s_feats[img])[t];
                float n = sqrtf(v.x * v.x + v.y * v.y + v.z * v.z + v.w * v.w);
                float inv = 1.0f / (n + 1e-12f);
                float e[4] = { v.x * inv, v.y * inv, v.z * inv, v.w * inv };
                #pragma unroll
                for (int k = 0; k < 4; ++k) {
                    uint32_t bx = __float_as_uint(e[k]);
                    uint32_t rh = bx + 0x7FFFu + ((bx >> 16) & 1u);   // RNE bf16
                    uint32_t hk = rh >> 16;
                    float hif = __uint_as_float(hk << 16);
                    float res = e[k] - hif;                            // exact
                    uint32_t br = __float_as_uint(res);
                    uint32_t rl = br + 0x7FFFu + ((br >> 16) & 1u);
                    pk[k]     = (short)hk;
                    pk[4 + k] = (short)(rl >> 16);
                }
            }
            *(v8s*)&s_P[img][t][0] = pk;
        }
    }
    __syncthreads();

    // Persistent zero C-operand: built once, pinned -> never re-materialized.
    v16f zacc = {0.f,0.f,0.f,0.f,0.f,0.f,0.f,0.f,
                 0.f,0.f,0.f,0.f,0.f,0.f,0.f,0.f};
    asm("" : "+v"(zacc));

    // ---- Phase 4: 14 jobs = (img, col-stripe j); wave takes jobs w, w+4, ...
    // A k-pack [h0..h3,l0..l3]; B half0 [h0..h3 x2], half1 [l0..l3 x2]
    // => contraction = exact (h+l).(h+l), invariant to k<->(half,j) mapping.
    for (int job = w; job < 14; job += 4) {
        const int img = (job >= 7) ? 1 : 0;
        const int j = job - 7 * img;
        const int ln = l & 31, half = l >> 5;

        v4s bh = *(const v4s*)&s_P[img][32 * j + ln][4 * half];
        v8s B = __builtin_shufflevector(bh, bh, 0, 1, 2, 3, 0, 1, 2, 3);

        unsigned cnt = 0u;
        #pragma unroll
        for (int i = 0; i < 7; ++i) {
            v8s A = *(const v8s*)&s_P[img][32 * i + ln][0];
            v16f acc = __builtin_amdgcn_mfma_f32_32x32x16_bf16(A, B, zacc, 0, 0, 0);
            #pragma unroll
            for (int e = 0; e < 16; ++e)
                cnt += (fabsf(acc[e]) >= COS_TH) ? 1u : 0u;
        }
        cnt += __shfl_down(cnt, 32, 64);   // merge the two row-halves
        if (l < 32) {
            int col = 32 * j + l;
            if (col < NP)
                s_feats[img][784 + col] = (float)(int)cnt - 1.0f;  // self-edge
        }
    }
    __syncthreads();

    // ---- Phase 5: linear, shared lin_w loads across both images ----
    if (t < 250) {
        int k = t / 25, c = t - 25 * (t / 25);
        const float4* wrow = (const float4*)(lin_w + k * FEAT);
        const float4* f0p = (const float4*)s_feats[0];
        const float4* f1p = (const float4*)s_feats[1];
        float a0 = 0.0f, a1 = 0.0f;
        for (int i = c; i < 245; i += 25) {
            float4 wv = wrow[i];
            float4 f0 = f0p[i];
            float4 f1 = f1p[i];
            a0 = fmaf(f0.x, wv.x, a0); a1 = fmaf(f1.x, wv.x, a1);
            a0 = fmaf(f0.y, wv.y, a0); a1 = fmaf(f1.y, wv.y, a1);
            a0 = fmaf(f0.z, wv.z, a0); a1 = fmaf(f1.z, wv.z, a1);
            a0 = fmaf(f0.w, wv.w, a0); a1 = fmaf(f1.w, wv.w, a1);
        }
        (s_x[0] + 256)[t] = a0;    // s_part0 (overlay)
        (s_x[1] + 256)[t] = a1;    // s_part1 (overlay)
    }
    __syncthreads();

    if (t < 20) {
        int img = t / 10, k = t - 10 * (t / 10);
        const float* part = s_x[img] + 256;
        float s = lin_b[k];
        #pragma unroll
        for (int i = 0; i < 25; ++i) s += part[k * 25 + i];
        (s_x[img] + 512)[k] = s;   // s_logits (overlay)
    }
    __syncthreads();

    // ---- Phase 6: log_softmax, both images in parallel lanes ----
    if (t < 20) {
        int img = t / 10, k = t - 10 * (t / 10);
        const float* lg = s_x[img] + 512;
        float m = -INFINITY;
        #pragma unroll
        for (int j2 = 0; j2 < 10; ++j2) m = fmaxf(m, lg[j2]);
        float s = 0.0f;
        #pragma unroll
        for (int j2 = 0; j2 < 10; ++j2) s += expf(lg[j2] - m);
        out[(size_t)(2 * b + img) * 10 + k] = lg[k] - m - logf(s);
    }
}

extern "C" void kernel_launch(void* const* d_in, const int* in_sizes, int n_in,
                              void* d_out, int out_size, void* d_ws, size_t ws_size,
                              hipStream_t stream) {
    const float* x      = (const float*)d_in[0];
    const float* conv_w = (const float*)d_in[1];
    const float* conv_b = (const float*)d_in[2];
    const float* lin_w  = (const float*)d_in[3];
    const float* lin_b  = (const float*)d_in[4];
    float* out = (float*)d_out;
    quanv_kernel<<<dim3(4096), dim3(256), 0, stream>>>(x, conv_w, conv_b, lin_w, lin_b, out);
}

// Round 17
// 107.271 us; speedup vs baseline: 1.0216x; 1.0216x over previous
//
#include <hip/hip_runtime.h>
#include <math.h>

// QuanvolutionHybrid: conv2x2/s2 -> reshape(196,4) -> L2 norm ->
// all-pairs cos^2 >= 0.8 -> degree -> concat(784+196) -> linear(10) -> log_softmax
// R17: R16 (MFMA pair phase + pinned zero C, 46us) + issue trims:
//      (a) job loop fully unrolled (4 predicated iters, hoisted bases);
//      (b) stripe-6 pad-skip: real rows 192..195 live only in regs 0..3 of
//          half=0 lanes (C layout: row=(reg&3)+8*(reg>>2)+4*(lane>>5), HW-
//          verified) -> skip 28/32 of the compares there. Provably inert:
//          pad rows are zero => |d|=0 < TH.
//      (c) two count accumulators (dep-chain split). Counting stays plain C
//          (R15 lesson: never feed MFMA dest regs into inline asm).

#define NP 196
#define FEAT 980
#define COS_TH 0.894427190999915878f   // sqrt(0.8)

typedef short v4s  __attribute__((ext_vector_type(4)));
typedef short v8s  __attribute__((ext_vector_type(8)));
typedef float v16f __attribute__((ext_vector_type(16)));

__global__ __launch_bounds__(256, 6) void quanv_kernel(
    const float* __restrict__ x,        // (8192, 784)
    const float* __restrict__ conv_w,   // (4,1,2,2) = 16
    const float* __restrict__ conv_b,   // (4,)
    const float* __restrict__ lin_w,    // (10, 980)
    const float* __restrict__ lin_b,    // (10,)
    float* __restrict__ out)            // (8192, 10)
{
    // s_x[img] dead after phase 2 -> late-phase overlays live on it.
    __shared__ __align__(16) float s_x[2][784];
    __shared__ __align__(16) short s_P[2][224][8];  // bf16 row: h0..h3, l0..l3
    __shared__ __align__(16) float s_feats[2][FEAT];

    const int b = blockIdx.x;            // 4096 blocks, 2 images each
    const int t = threadIdx.x;
    const int w = t >> 6, l = t & 63;

    // ---- Phase 1: stage both images ----
    if (t < NP) {
        ((float4*)s_x[0])[t] = ((const float4*)(x + (size_t)(2 * b)     * 784))[t];
        ((float4*)s_x[1])[t] = ((const float4*)(x + (size_t)(2 * b + 1) * 784))[t];
    }
    __syncthreads();

    // ---- Phase 2: conv both -> s_feats[img][0..784) channel-major ----
    if (t < NP) {
        int h = t / 14, ww = t - 14 * (t / 14);
        #pragma unroll
        for (int img = 0; img < 2; ++img) {
            const float* r0 = s_x[img] + (2 * h) * 28 + 2 * ww;
            float x00 = r0[0], x01 = r0[1], x10 = r0[28], x11 = r0[29];
            #pragma unroll
            for (int c = 0; c < 4; ++c) {
                float f = conv_b[c]
                        + conv_w[c * 4 + 0] * x00 + conv_w[c * 4 + 1] * x01
                        + conv_w[c * 4 + 2] * x10 + conv_w[c * 4 + 3] * x11;
                s_feats[img][c * NP + t] = f;
            }
        }
    }
    __syncthreads();   // s_x dead; overlays usable after this barrier

    // ---- Phase 3: normalize + exact bf16 hi/lo split -> s_P (rows 196..223 = 0) ----
    if (t < 224) {
        #pragma unroll
        for (int img = 0; img < 2; ++img) {
            v8s pk = {0, 0, 0, 0, 0, 0, 0, 0};
            if (t < NP) {
                float4 v = ((const float4*)s_feats[img])[t];
                float n = sqrtf(v.x * v.x + v.y * v.y + v.z * v.z + v.w * v.w);
                float inv = 1.0f / (n + 1e-12f);
                float e[4] = { v.x * inv, v.y * inv, v.z * inv, v.w * inv };
                #pragma unroll
                for (int k = 0; k < 4; ++k) {
                    uint32_t bx = __float_as_uint(e[k]);
                    uint32_t rh = bx + 0x7FFFu + ((bx >> 16) & 1u);   // RNE bf16
                    uint32_t hk = rh >> 16;
                    float hif = __uint_as_float(hk << 16);
                    float res = e[k] - hif;                            // exact
                    uint32_t br = __float_as_uint(res);
                    uint32_t rl = br + 0x7FFFu + ((br >> 16) & 1u);
                    pk[k]     = (short)hk;
                    pk[4 + k] = (short)(rl >> 16);
                }
            }
            *(v8s*)&s_P[img][t][0] = pk;
        }
    }
    __syncthreads();

    // Persistent zero C-operand: built once, pinned -> never re-materialized.
    v16f zacc = {0.f,0.f,0.f,0.f,0.f,0.f,0.f,0.f,
                 0.f,0.f,0.f,0.f,0.f,0.f,0.f,0.f};
    asm("" : "+v"(zacc));

    // ---- Phase 4: 14 jobs = (img, col-stripe j); wave w takes w, w+4, w+8, w+12.
    // A k-pack [h0..h3,l0..l3]; B half0 [h0..h3 x2], half1 [l0..l3 x2]
    // => contraction = exact (h+l).(h+l), invariant to k<->(half,j) mapping.
    const int ln = l & 31, half = l >> 5;
    #pragma unroll
    for (int jj = 0; jj < 4; ++jj) {
        const int job = w + 4 * jj;
        if (job < 14) {
            const int img = (job >= 7) ? 1 : 0;
            const int j = job - 7 * img;
            const short* Pbase = &s_P[img][0][0];

            v4s bh = *(const v4s*)(Pbase + (32 * j + ln) * 8 + 4 * half);
            v8s B = __builtin_shufflevector(bh, bh, 0, 1, 2, 3, 0, 1, 2, 3);

            unsigned c0 = 0u, c1 = 0u;
            #pragma unroll
            for (int i = 0; i < 6; ++i) {
                v8s A = *(const v8s*)(Pbase + (32 * i + ln) * 8);
                v16f acc = __builtin_amdgcn_mfma_f32_32x32x16_bf16(A, B, zacc, 0, 0, 0);
                #pragma unroll
                for (int e = 0; e < 16; e += 2) {
                    c0 += (fabsf(acc[e])     >= COS_TH) ? 1u : 0u;
                    c1 += (fabsf(acc[e + 1]) >= COS_TH) ? 1u : 0u;
                }
            }
            // Stripe i=6: only rows 192..195 are real = local rows 0..3 =
            // regs 0..3 of half==0 lanes (row=(reg&3)+8*(reg>>2)+4*half).
            // Pad rows are exact zeros => skipping their compares is inert.
            {
                v8s A = *(const v8s*)(Pbase + (32 * 6 + ln) * 8);
                v16f acc = __builtin_amdgcn_mfma_f32_32x32x16_bf16(A, B, zacc, 0, 0, 0);
                if (half == 0) {
                    c0 += (fabsf(acc[0]) >= COS_TH) ? 1u : 0u;
                    c1 += (fabsf(acc[1]) >= COS_TH) ? 1u : 0u;
                    c0 += (fabsf(acc[2]) >= COS_TH) ? 1u : 0u;
                    c1 += (fabsf(acc[3]) >= COS_TH) ? 1u : 0u;
                }
            }
            unsigned cnt = c0 + c1;
            cnt += __shfl_down(cnt, 32, 64);   // merge the two row-halves
            if (l < 32) {
                int col = 32 * j + l;
                if (col < NP)
                    s_feats[img][784 + col] = (float)(int)cnt - 1.0f;  // self-edge
            }
        }
    }
    __syncthreads();

    // ---- Phase 5: linear, shared lin_w loads across both images ----
    if (t < 250) {
        int k = t / 25, c = t - 25 * (t / 25);
        const float4* wrow = (const float4*)(lin_w + k * FEAT);
        const float4* f0p = (const float4*)s_feats[0];
        const float4* f1p = (const float4*)s_feats[1];
        float a0 = 0.0f, a1 = 0.0f;
        for (int i = c; i < 245; i += 25) {
            float4 wv = wrow[i];
            float4 f0 = f0p[i];
            float4 f1 = f1p[i];
            a0 = fmaf(f0.x, wv.x, a0); a1 = fmaf(f1.x, wv.x, a1);
            a0 = fmaf(f0.y, wv.y, a0); a1 = fmaf(f1.y, wv.y, a1);
            a0 = fmaf(f0.z, wv.z, a0); a1 = fmaf(f1.z, wv.z, a1);
            a0 = fmaf(f0.w, wv.w, a0); a1 = fmaf(f1.w, wv.w, a1);
        }
        (s_x[0] + 256)[t] = a0;    // s_part0 (overlay)
        (s_x[1] + 256)[t] = a1;    // s_part1 (overlay)
    }
    __syncthreads();

    if (t < 20) {
        int img = t / 10, k = t - 10 * (t / 10);
        const float* part = s_x[img] + 256;
        float s = lin_b[k];
        #pragma unroll
        for (int i = 0; i < 25; ++i) s += part[k * 25 + i];
        (s_x[img] + 512)[k] = s;   // s_logits (overlay)
    }
    __syncthreads();

    // ---- Phase 6: log_softmax, both images in parallel lanes ----
    if (t < 20) {
        int img = t / 10, k = t - 10 * (t / 10);
        const float* lg = s_x[img] + 512;
        float m = -INFINITY;
        #pragma unroll
        for (int j2 = 0; j2 < 10; ++j2) m = fmaxf(m, lg[j2]);
        float s = 0.0f;
        #pragma unroll
        for (int j2 = 0; j2 < 10; ++j2) s += expf(lg[j2] - m);
        out[(size_t)(2 * b + img) * 10 + k] = lg[k] - m - logf(s);
    }
}

extern "C" void kernel_launch(void* const* d_in, const int* in_sizes, int n_in,
                              void* d_out, int out_size, void* d_ws, size_t ws_size,
                              hipStream_t stream) {
    const float* x      = (const float*)d_in[0];
    const float* conv_w = (const float*)d_in[1];
    const float* conv_b = (const float*)d_in[2];
    const float* lin_w  = (const float*)d_in[3];
    const float* lin_b  = (const float*)d_in[4];
    float* out = (float*)d_out;
    quanv_kernel<<<dim3(4096), dim3(256), 0, stream>>>(x, conv_w, conv_b, lin_w, lin_b, out);
}

// Round 18
// 104.365 us; speedup vs baseline: 1.0501x; 1.0278x over previous
//
#include <hip/hip_runtime.h>
#include <math.h>

// QuanvolutionHybrid: conv2x2/s2 -> reshape(196,4) -> L2 norm ->
// all-pairs cos^2 >= 0.8 -> degree -> concat(784+196) -> linear(10) -> log_softmax
// R18: 192-aligned MFMA core. R17's 7x7 stripe grid had 14 jobs / 4 waves
//      (imbalanced, critical path 28 tiles) and 23% pad waste. Now:
//      - MFMA covers rows/cols 0..191 only: 12 jobs (2img x 6 colstripes),
//        exactly 3 jobs/wave, 6 MFMAs each -> critical path 18 tiles.
//      - Boundary rows 192..195: R6-proven ballot/popcount tail (wave w owns
//        row 192+w, both images), fp32 dots reconstructed as h+l (consistent
//        with the split path). Cross-credits to deg[q<192] via sparse LDS
//        atomics into a separate pre-zeroed s_cred (no race with 4a stores).
//      Counting stays plain C on MFMA results (R15 lesson). zacc pinned (R16).

#define NP 196
#define FEAT 980
#define COS_TH 0.894427190999915878f   // sqrt(0.8)

typedef short v4s  __attribute__((ext_vector_type(4)));
typedef short v8s  __attribute__((ext_vector_type(8)));
typedef float v16f __attribute__((ext_vector_type(16)));

static __device__ __forceinline__ float bf2f(short s) {
    return __uint_as_float(((uint32_t)(uint16_t)s) << 16);
}

__global__ __launch_bounds__(256, 6) void quanv_kernel(
    const float* __restrict__ x,        // (8192, 784)
    const float* __restrict__ conv_w,   // (4,1,2,2) = 16
    const float* __restrict__ conv_b,   // (4,)
    const float* __restrict__ lin_w,    // (10, 980)
    const float* __restrict__ lin_b,    // (10,)
    float* __restrict__ out)            // (8192, 10)
{
    // s_x[img] dead after phase 2 -> overlays:
    //   s_deg [2][192] ints | s_cred [2][196] ints | s_part [2][250] | s_logits [2][10]
    __shared__ __align__(16) float s_x[2][784];
    __shared__ __align__(16) short s_P[2][256][8];  // bf16 row: h0..h3,l0..l3; rows>=196 zero
    __shared__ __align__(16) float s_feats[2][FEAT];

    int*   s_deg    = (int*)s_x;            // [2][192]
    int*   s_cred   = s_deg + 384;          // [2][196]
    float* s_part   = (float*)(s_cred + 392); // [2][250]
    float* s_logits = s_part + 500;         // [2][10]

    const int b = blockIdx.x;            // 4096 blocks, 2 images each
    const int t = threadIdx.x;
    const int w = t >> 6, l = t & 63;

    // ---- Phase 1: stage both images ----
    if (t < NP) {
        ((float4*)s_x[0])[t] = ((const float4*)(x + (size_t)(2 * b)     * 784))[t];
        ((float4*)s_x[1])[t] = ((const float4*)(x + (size_t)(2 * b + 1) * 784))[t];
    }
    __syncthreads();

    // ---- Phase 2: conv both -> s_feats[img][0..784) channel-major ----
    if (t < NP) {
        int h = t / 14, ww = t - 14 * (t / 14);
        #pragma unroll
        for (int img = 0; img < 2; ++img) {
            const float* r0 = s_x[img] + (2 * h) * 28 + 2 * ww;
            float x00 = r0[0], x01 = r0[1], x10 = r0[28], x11 = r0[29];
            #pragma unroll
            for (int c = 0; c < 4; ++c) {
                float f = conv_b[c]
                        + conv_w[c * 4 + 0] * x00 + conv_w[c * 4 + 1] * x01
                        + conv_w[c * 4 + 2] * x10 + conv_w[c * 4 + 3] * x11;
                s_feats[img][c * NP + t] = f;
            }
        }
    }
    __syncthreads();   // s_x dead; overlays usable after this barrier

    // ---- Phase 3: normalize + exact bf16 hi/lo split -> s_P; zero pads + cred ----
    {
        #pragma unroll
        for (int img = 0; img < 2; ++img) {
            v8s pk = {0, 0, 0, 0, 0, 0, 0, 0};
            if (t < NP) {
                float4 v = ((const float4*)s_feats[img])[t];
                float n = sqrtf(v.x * v.x + v.y * v.y + v.z * v.z + v.w * v.w);
                float inv = 1.0f / (n + 1e-12f);
                float e[4] = { v.x * inv, v.y * inv, v.z * inv, v.w * inv };
                #pragma unroll
                for (int k = 0; k < 4; ++k) {
                    uint32_t bx = __float_as_uint(e[k]);
                    uint32_t rh = bx + 0x7FFFu + ((bx >> 16) & 1u);   // RNE bf16
                    uint32_t hk = rh >> 16;
                    float hif = __uint_as_float(hk << 16);
                    float res = e[k] - hif;                            // exact
                    uint32_t br = __float_as_uint(res);
                    uint32_t rl = br + 0x7FFFu + ((br >> 16) & 1u);
                    pk[k]     = (short)hk;
                    pk[4 + k] = (short)(rl >> 16);
                }
            }
            *(v8s*)&s_P[img][t][0] = pk;
        }
        if (t < NP) { s_cred[t] = 0; s_cred[196 + t] = 0; }
    }
    __syncthreads();

    // Persistent zero C-operand: built once, pinned.
    v16f zacc = {0.f,0.f,0.f,0.f,0.f,0.f,0.f,0.f,
                 0.f,0.f,0.f,0.f,0.f,0.f,0.f,0.f};
    asm("" : "+v"(zacc));

    const int ln = l & 31, half = l >> 5;

    // ---- Phase 4a: MFMA core, rows/cols 0..191. 12 jobs, 3/wave, 6 tiles each.
    #pragma unroll
    for (int jj = 0; jj < 3; ++jj) {
        const int job = w + 4 * jj;          // 0..11, wave-uniform
        const int img = (job >= 6) ? 1 : 0;
        const int j = job - 6 * img;
        const short* Pbase = &s_P[img][0][0];

        v4s bh = *(const v4s*)(Pbase + (32 * j + ln) * 8 + 4 * half);
        v8s B = __builtin_shufflevector(bh, bh, 0, 1, 2, 3, 0, 1, 2, 3);

        unsigned c0 = 0u, c1 = 0u;
        #pragma unroll
        for (int i = 0; i < 6; ++i) {
            v8s A = *(const v8s*)(Pbase + (32 * i + ln) * 8);
            v16f acc = __builtin_amdgcn_mfma_f32_32x32x16_bf16(A, B, zacc, 0, 0, 0);
            #pragma unroll
            for (int e = 0; e < 16; e += 2) {
                c0 += (fabsf(acc[e])     >= COS_TH) ? 1u : 0u;
                c1 += (fabsf(acc[e + 1]) >= COS_TH) ? 1u : 0u;
            }
        }
        unsigned cnt = c0 + c1;
        cnt += __shfl_down(cnt, 32, 64);   // merge the two row-halves
        if (l < 32)
            s_deg[img * 192 + 32 * j + l] = (int)cnt;
    }

    // ---- Phase 4b: boundary rows 192..195 (wave w owns row 192+w, both imgs).
    // fp32 dots from reconstructed h+l (consistent with split-path values).
    #pragma unroll
    for (int img = 0; img < 2; ++img) {
        const int r = 192 + w;
        const short* pr = &s_P[img][r][0];
        float pe0 = bf2f(pr[0]) + bf2f(pr[4]);
        float pe1 = bf2f(pr[1]) + bf2f(pr[5]);
        float pe2 = bf2f(pr[2]) + bf2f(pr[6]);
        float pe3 = bf2f(pr[3]) + bf2f(pr[7]);
        unsigned total = 0u;
        #pragma unroll
        for (int k = 0; k < 4; ++k) {
            int q = 64 * k + l;              // rows >=196 are zero -> miss
            const short* qr = &s_P[img][q][0];
            float d =          pe0 * (bf2f(qr[0]) + bf2f(qr[4]));
            d = fmaf(pe1, bf2f(qr[1]) + bf2f(qr[5]), d);
            d = fmaf(pe2, bf2f(qr[2]) + bf2f(qr[6]), d);
            d = fmaf(pe3, bf2f(qr[3]) + bf2f(qr[7]), d);
            bool hit = fabsf(d) >= COS_TH;
            unsigned long long m = __ballot(hit);
            total += (unsigned)__popcll(m);
            if (hit && q < 192)
                atomicAdd(&s_cred[img * 196 + q], 1);   // sparse (~4%)
        }
        if (l == 0)
            s_feats[img][784 + r] = (float)(int)total - 1.0f;  // self-edge
    }
    __syncthreads();

    // ---- Phase 4c: combine core counts + boundary credits -> deg features ----
    if (t < 192) {
        s_feats[0][784 + t] = (float)(s_deg[t]       + s_cred[t])       - 1.0f;
        s_feats[1][784 + t] = (float)(s_deg[192 + t] + s_cred[196 + t]) - 1.0f;
    }
    __syncthreads();

    // ---- Phase 5: linear, shared lin_w loads across both images ----
    if (t < 250) {
        int k = t / 25, c = t - 25 * (t / 25);
        const float4* wrow = (const float4*)(lin_w + k * FEAT);
        const float4* f0p = (const float4*)s_feats[0];
        const float4* f1p = (const float4*)s_feats[1];
        float a0 = 0.0f, a1 = 0.0f;
        for (int i = c; i < 245; i += 25) {
            float4 wv = wrow[i];
            float4 f0 = f0p[i];
            float4 f1 = f1p[i];
            a0 = fmaf(f0.x, wv.x, a0); a1 = fmaf(f1.x, wv.x, a1);
            a0 = fmaf(f0.y, wv.y, a0); a1 = fmaf(f1.y, wv.y, a1);
            a0 = fmaf(f0.z, wv.z, a0); a1 = fmaf(f1.z, wv.z, a1);
            a0 = fmaf(f0.w, wv.w, a0); a1 = fmaf(f1.w, wv.w, a1);
        }
        s_part[t]       = a0;
        s_part[250 + t] = a1;
    }
    __syncthreads();

    if (t < 20) {
        int img = t / 10, k = t - 10 * (t / 10);
        const float* part = s_part + 250 * img;
        float s = lin_b[k];
        #pragma unroll
        for (int i = 0; i < 25; ++i) s += part[k * 25 + i];
        s_logits[10 * img + k] = s;
    }
    __syncthreads();

    // ---- Phase 6: log_softmax, both images in parallel lanes ----
    if (t < 20) {
        int img = t / 10, k = t - 10 * (t / 10);
        const float* lg = s_logits + 10 * img;
        float m = -INFINITY;
        #pragma unroll
        for (int j2 = 0; j2 < 10; ++j2) m = fmaxf(m, lg[j2]);
        float s = 0.0f;
        #pragma unroll
        for (int j2 = 0; j2 < 10; ++j2) s += expf(lg[j2] - m);
        out[(size_t)(2 * b + img) * 10 + k] = lg[k] - m - logf(s);
    }
}

extern "C" void kernel_launch(void* const* d_in, const int* in_sizes, int n_in,
                              void* d_out, int out_size, void* d_ws, size_t ws_size,
                              hipStream_t stream) {
    const float* x      = (const float*)d_in[0];
    const float* conv_w = (const float*)d_in[1];
    const float* conv_b = (const float*)d_in[2];
    const float* lin_w  = (const float*)d_in[3];
    const float* lin_b  = (const float*)d_in[4];
    float* out = (float*)d_out;
    quanv_kernel<<<dim3(4096), dim3(256), 0, stream>>>(x, conv_w, conv_b, lin_w, lin_b, out);
}